// Round 11
// baseline (171.908 us; speedup 1.0000x reference)
//
#include <hip/hip_runtime.h>
#include <hip/hip_bf16.h>
#include <math.h>

// H2R detector: score map -> 3x3 NMS peaks -> per-batch top-1000 -> ROIs.
// [B=32,1,512,512] fp32 inputs; out = rois[32,1000,5] ++ scores[32,1000]
// ++ valid[32,1000] = 224000 floats.
//
// Scoring replicates numpy's SIMD (Cephes) fp32 expf op-for-op (verified
// bit-exact rounds 5-10: absmax 0.0). DO NOT alter score or emit paths.
//
// Round 22: select2 was ~45us across ALL variants because it ran 32 blocks
// (4.8% occupancy) through serial latency-bound phases. Dispatch boundaries
// measured ~free (R9/R10 additive). So: split select across the machine.
//   memset ghist -> fused_peak (R10 verbatim) ->
//   hist_kernel  (8x32 blocks): segs -> LDS fine hist -> global merge
//                (non-returning atomicAdd; not R1's returning-RMW trap)
//   scatter      (8x32 blocks): ghist -> deterministic T-scan -> append own
//                segments' >=T keys to PRIVATE region + plain count store
//   rank_emit    (32 blocks): compact 8 counted regions -> LDS full-scan
//                rank (nc~1050 broadcast iters) -> verbatim emit.
// Selection set / T rule / exact 64-bit descending order bit-identical.
// Fallback (sum ghist < K; never taken): R10 in-block recompute, verbatim.

#define B_   32
#define H_   512
#define W_   512
#define HW_  (H_ * W_)
#define K_   1000
#define ROWS_ 16            // interior rows per strip
#define THR_  512           // threads per fused block (8 waves)
#define NSTRIP_ 32          // H_/ROWS_
#define NBUK_ 4096          // coarse buckets (fallback only)
#define NFB_  2048          // fine buckets over [0.5, 1.0)
#define GCAP_ 2048          // candidate LDS capacity (nc ~ 1000-1050)
#define HSEG_ 128           // per-wave hot capacity (mean ~55, ~10 sigma)
#define NSEGB_ (NSTRIP_ * 8)               // 256 wave-segs per batch
#define GSP_  8             // hist/scatter splits per batch (32 segs each)
#define CAPSP_ 512          // per-split candidate capacity (mean ~130)
#define HOTBITS_ 0x3F000000u               // fp32 bits of 0.5f
#define FBCAP_ 45056                       // fallback per-batch peak capacity

#define HL_BYTES_  ((size_t)B_ * NSEGB_ * HSEG_ * 8)      // 8,388,608
#define HC_BYTES_  ((size_t)B_ * NSEGB_ * 4)              // 32,768
#define GH_BYTES_  ((size_t)B_ * NFB_ * 4)                // 262,144
#define GN_BYTES_  ((size_t)B_ * GSP_ * 4)                // 1,024
#define GC_BYTES_  ((size_t)B_ * GSP_ * CAPSP_ * 8)       // 1,048,576

// ---- numpy SIMD (Cephes) fp32 exp replica — bit-exact, do not touch -------
__device__ __forceinline__ float np_expf(float x) {
#pragma clang fp contract(off)
    const float log2e = 1.44269504088896341f;
    float z = x * log2e;
    float m = rintf(z);
    float r = fmaf(m, -0.693359375f, x);
    r = fmaf(m, 2.12194440e-4f, r);
    float r2 = r * r;
    float p = fmaf(1.9875691500e-4f, r, 1.3981999507e-3f);
    p = fmaf(p, r, 8.3334519073e-3f);
    p = fmaf(p, r, 4.1665795894e-2f);
    p = fmaf(p, r, 1.6666665459e-1f);
    p = fmaf(p, r, 5.0000001201e-1f);
    p = fmaf(p, r2, r);
    p = p + 1.0f;
    int mi = (int)m;
    float sc = __int_as_float((127 + mi) << 23);
    return p * sc;
}

__device__ __forceinline__ float sigmoid_np(float x) {
#pragma clang fp contract(off)
    float e = np_expf(-x);
    float d = 1.0f + e;
    return 1.0f / d;
}

__device__ __forceinline__ float score_ref(float r, float u) {
#pragma clang fp contract(off)
    float s  = sigmoid_np(r);
    float s2 = s * s;
    float su = sigmoid_np(u);
    float t  = 0.35f * su;
    float m  = 1.0f - t;
    return s2 * m;
}

__device__ __forceinline__ float sigmoid_fast(float x) {  // box geometry only
    return 1.0f / (1.0f + __expf(-x));
}

// ---- Fused: score strip + 3x3 peak test -> per-wave hot segments ----------
__global__ __launch_bounds__(THR_, 4) void fused_peak_kernel(
    const float* __restrict__ route, const float* __restrict__ unc,
    unsigned long long* __restrict__ hotlist,
    int* __restrict__ hcnt8)
{
    __shared__ float sm[ROWS_ + 2][W_];          // 18x512 = 36.9 KB

    const int tid   = threadIdx.x;
    const int lane  = tid & 63;
    const int wid   = tid >> 6;                  // 0..7
    const int strip = blockIdx.x;                // 0..31
    const int b     = blockIdx.y;                // 0..31
    const int r0    = strip * ROWS_;

    const float4* rb4 = (const float4*)(route + (size_t)b * HW_);
    const float4* ub4 = (const float4*)(unc   + (size_t)b * HW_);
    unsigned long long* hseg =
        hotlist + ((size_t)(b * NSTRIP_ + strip) * 8 + wid) * HSEG_;

    // Stage 18 halo rows: branchless (slot clamp), 10 loads in flight.
    float4 rv[5], uv[5];
    int lrow[5], c4[5]; bool ok[5];
    #pragma unroll
    for (int k = 0; k < 5; ++k) {
        int slot = tid + k * THR_;
        slot = slot < 2303 ? slot : 2303;
        int row = slot >> 7;
        int gy  = r0 - 1 + row;
        lrow[k] = row; c4[k] = slot & 127;
        ok[k]   = (gy >= 0 && gy < H_);
        int cy  = gy < 0 ? 0 : (gy >= H_ ? H_ - 1 : gy);
        rv[k] = rb4[cy * 128 + c4[k]];
        uv[k] = ub4[cy * 128 + c4[k]];
    }
    #pragma unroll
    for (int k = 0; k < 5; ++k) {
        float4 s;
        s.x = score_ref(rv[k].x, uv[k].x);
        s.y = score_ref(rv[k].y, uv[k].y);
        s.z = score_ref(rv[k].z, uv[k].z);
        s.w = score_ref(rv[k].w, uv[k].w);
        if (!ok[k]) { s.x = -INFINITY; s.y = -INFINITY;
                      s.z = -INFINITY; s.w = -INFINITY; }
        *(float4*)&sm[lrow[k]][c4[k] * 4] = s;
    }
    __syncthreads();

    // Peak test: 16x512 interior, 4-px groups, float4 reads + column max.
    // Hot peaks (bits >= 0.5f): per-wave register-counter append.
    const unsigned long long lt = (1ull << lane) - 1ull;
    int wn = 0;                                  // wave-uniform hot count
    #pragma unroll
    for (int j = 0; j < 4; ++j) {
        int g  = tid + j * THR_;                 // 0..2047
        int ly = 1 + (g >> 7);                   // 1..16
        int x0 = (g & 127) * 4;
        int gy = r0 + (ly - 1);
        float4 q0 = *(const float4*)&sm[ly - 1][x0];
        float4 q1 = *(const float4*)&sm[ly    ][x0];
        float4 q2 = *(const float4*)&sm[ly + 1][x0];
        bool hasL = (x0 > 0), hasR = (x0 + 4 < W_);
        float l0 = hasL ? sm[ly - 1][x0 - 1] : -INFINITY;
        float l1 = hasL ? sm[ly    ][x0 - 1] : -INFINITY;
        float l2 = hasL ? sm[ly + 1][x0 - 1] : -INFINITY;
        float e0 = hasR ? sm[ly - 1][x0 + 4] : -INFINITY;
        float e1 = hasR ? sm[ly    ][x0 + 4] : -INFINITY;
        float e2 = hasR ? sm[ly + 1][x0 + 4] : -INFINITY;
        float f_m1 = fmaxf(l0, fmaxf(l1, l2));
        float f_0  = fmaxf(q0.x, fmaxf(q1.x, q2.x));
        float f_1  = fmaxf(q0.y, fmaxf(q1.y, q2.y));
        float f_2  = fmaxf(q0.z, fmaxf(q1.z, q2.z));
        float f_3  = fmaxf(q0.w, fmaxf(q1.w, q2.w));
        float f_4  = fmaxf(e0, fmaxf(e1, e2));
        float tb0  = fmaxf(q0.x, q2.x);
        float tb1  = fmaxf(q0.y, q2.y);
        float tb2  = fmaxf(q0.z, q2.z);
        float tb3  = fmaxf(q0.w, q2.w);
        float vv[4] = { q1.x, q1.y, q1.z, q1.w };
        float mm[4];
        mm[0] = fmaxf(fmaxf(f_m1, f_1), tb0);
        mm[1] = fmaxf(fmaxf(f_0,  f_2), tb1);
        mm[2] = fmaxf(fmaxf(f_1,  f_3), tb2);
        mm[3] = fmaxf(fmaxf(f_2,  f_4), tb3);
        #pragma unroll
        for (int i = 0; i < 4; ++i) {
            bool take = (vv[i] >= mm[i]);
            unsigned int bits = __float_as_uint(vv[i]);
            bool hot = take && (bits >= HOTBITS_);
            unsigned long long hmk = __ballot(hot);
            if (hot) {
                int hp = wn + __popcll(hmk & lt);
                if (hp < HSEG_) {
                    unsigned int idx = (unsigned int)(gy * W_ + x0 + i);
                    hseg[hp] = ((unsigned long long)bits << 32)
                               | (0xFFFFFFFFu - idx);
                }
            }
            wn += __popcll(hmk);
        }
    }
    if (lane == 0)
        hcnt8[(b * NSTRIP_ + strip) * 8 + wid] = wn < HSEG_ ? wn : HSEG_;
}

// ---- hist: 8 blocks/batch stream segments -> LDS fine hist -> global merge
__global__ __launch_bounds__(512) void hist_kernel(
    const unsigned long long* __restrict__ hotlist,
    const int* __restrict__ hcnt8,
    unsigned int* __restrict__ ghist)
{
    __shared__ unsigned int hh[NFB_];            // 8 KB
    __shared__ int segc[32];

    const int sp = blockIdx.x, b = blockIdx.y, tid = threadIdx.x;
    const int lane = tid & 63, wid = tid >> 6;
    for (int i = tid; i < NFB_; i += 512) hh[i] = 0u;
    if (tid < 32) segc[tid] = hcnt8[b * NSEGB_ + sp * 32 + tid];
    __syncthreads();

    const unsigned long long* hb =
        hotlist + ((size_t)b * NSEGB_ + sp * 32) * HSEG_;
    for (int s = wid; s < 32; s += 8) {
        int c = segc[s];
        const unsigned long long* hs = hb + (size_t)s * HSEG_;
        for (int base = 0; base < c; base += 64) {
            int i = base + lane;
            if (i < c) {
                unsigned int bits = (unsigned int)(hs[i] >> 32);
                unsigned int fbk = (bits - HOTBITS_) >> 12;
                if (fbk > NFB_ - 1u) fbk = NFB_ - 1u;
                atomicAdd(&hh[fbk], 1u);
            }
        }
    }
    __syncthreads();

    // Non-returning global merge (fire-and-forget; ghist memset to 0).
    unsigned int* gh = ghist + (size_t)b * NFB_;
    for (int i = tid; i < NFB_; i += 512) {
        unsigned int v = hh[i];
        if (v) atomicAdd(&gh[i], v);
    }
}

// ---- scatter: deterministic T-scan -> append own >=T keys to private seg -
__global__ __launch_bounds__(512) void scatter_kernel(
    const unsigned long long* __restrict__ hotlist,
    const int* __restrict__ hcnt8,
    const unsigned int* __restrict__ ghist,
    unsigned long long* __restrict__ gcand,
    int* __restrict__ gncnt)
{
    __shared__ unsigned int gh[NFB_];            // 8 KB
    __shared__ int segc[32];
    __shared__ int sh_T, sh_n;

    const int sp = blockIdx.x, b = blockIdx.y, tid = threadIdx.x;
    const int lane = tid & 63, wid = tid >> 6;
    const unsigned long long lt = (1ull << lane) - 1ull;

    for (int i = tid; i < NFB_; i += 512) gh[i] = ghist[(size_t)b * NFB_ + i];
    if (tid < 32) segc[tid] = hcnt8[b * NSEGB_ + sp * 32 + tid];
    if (tid == 0) { sh_T = -1; sh_n = 0; }
    __syncthreads();

    // Wave0: T = largest bucket with count(>=T) >= K (identical across the
    // batch's 8 blocks: same ghist, same integer computation).
    if (wid == 0) {
        int total = 0;
        for (int c = NFB_ / 64 - 1; c >= 0; --c) {
            int cnt = (int)gh[c * 64 + lane];
            int sum = cnt;
            #pragma unroll
            for (int off = 32; off > 0; off >>= 1)
                sum += __shfl_down(sum, off, 64);
            sum = __shfl(sum, 0, 64);
            if (total + sum < K_) { total += sum; continue; }
            int suf = cnt;                       // inclusive suffix over lanes
            #pragma unroll
            for (int off = 1; off < 64; off <<= 1) {
                int o = __shfl_down(suf, off, 64);
                suf += (lane + off < 64) ? o : 0;
            }
            bool cond = (total + suf) >= K_;
            unsigned long long mask = __ballot(cond);
            int ls = 63 - __builtin_clzll(mask);
            if (lane == 0) sh_T = c * 64 + ls;
            break;
        }
    }
    __syncthreads();
    const int T = sh_T;
    if (T < 0) {                                 // fallback: rank_emit handles
        if (tid == 0) gncnt[b * GSP_ + sp] = 0;
        return;
    }

    unsigned long long* cd = gcand + ((size_t)b * GSP_ + sp) * CAPSP_;
    const unsigned long long* hb =
        hotlist + ((size_t)b * NSEGB_ + sp * 32) * HSEG_;
    for (int s = wid; s < 32; s += 8) {
        int c = segc[s];
        const unsigned long long* hs = hb + (size_t)s * HSEG_;
        for (int base = 0; base < c; base += 64) {
            int i = base + lane;
            bool take = false;
            unsigned long long key = 0ull;
            if (i < c) {
                key = hs[i];
                unsigned int bits = (unsigned int)(key >> 32);
                unsigned int fbk = (bits - HOTBITS_) >> 12;
                if (fbk > NFB_ - 1u) fbk = NFB_ - 1u;
                take = ((int)fbk >= T);
            }
            unsigned long long mk = __ballot(take);
            if (mk) {
                int ldr = __ffsll(mk) - 1;
                int bp = 0;
                if (lane == ldr) bp = atomicAdd(&sh_n, __popcll(mk));
                bp = __shfl(bp, ldr, 64);
                if (take) {
                    int p = bp + __popcll(mk & lt);
                    if (p < CAPSP_) cd[p] = key;
                }
            }
        }
    }
    __syncthreads();
    if (tid == 0) {
        int n = sh_n; if (n > CAPSP_) n = CAPSP_;
        gncnt[b * GSP_ + sp] = n;
    }
}

// ---- rank_emit: compact 8 regions -> full-scan exact rank -> emit ---------
// LDS overlay: u_ = sm[18][512] in the fallback strip loop, cursor+grp after
// (fast path uses only grp at u_+16384).
__global__ __launch_bounds__(1024) void rank_emit_kernel(
    const float* __restrict__ route, const float* __restrict__ unc_r,
    const float* __restrict__ scale, const float* __restrict__ unc,
    const unsigned int* __restrict__ ghist,
    const unsigned long long* __restrict__ gcand,
    const int* __restrict__ gncnt,
    unsigned long long* __restrict__ fbbuf,
    const int* __restrict__ ih_p, const int* __restrict__ iw_p,
    float* __restrict__ out)
{
    __shared__ __align__(16) unsigned char u_[(ROWS_ + 2) * W_ * 4]; // 36.9 KB
    __shared__ unsigned int hist[NBUK_];          // 16 KB (fallback coarse)
    __shared__ int offs[GSP_ + 1];
    __shared__ int sh_tot, sh_T, sh_nc, sh_fn;

    float (*sm)[W_] = (float (*)[W_])u_;
    unsigned int* cursor = (unsigned int*)u_;                        // 16 KB
    unsigned long long* grp = (unsigned long long*)(u_ + 16384);     // 16 KB

    const int b = blockIdx.x, tid = threadIdx.x;
    const int lane = tid & 63, wid = tid >> 6;

    const float fih = (float)(*ih_p);
    const float fiw = (float)(*iw_p);
    float* rois   = out;                       // [B,K,5]
    float* scores = out + (size_t)B_ * K_ * 5; // [B,K]
    float* validf = out + (size_t)B_ * K_ * 6; // [B,K]

    // Total hot count from ghist -> fallback decision.
    if (tid == 0) { sh_tot = 0; sh_T = 0; sh_nc = 0; sh_fn = 0; }
    __syncthreads();
    {
        const unsigned int* gh = ghist + (size_t)b * NFB_;
        int t = 0;
        for (int i = tid; i < NFB_; i += 1024) t += (int)gh[i];
        #pragma unroll
        for (int off = 32; off > 0; off >>= 1)
            t += __shfl_down(t, off, 64);
        if (lane == 0) atomicAdd(&sh_tot, t);
    }
    __syncthreads();

    if (sh_tot >= K_) {
        // ---- Fast path: compact the 8 counted regions into grp ----
        if (tid == 0) {
            int r = 0;
            #pragma unroll
            for (int s = 0; s < GSP_; ++s) {
                offs[s] = r;
                r += gncnt[b * GSP_ + s];
            }
            offs[GSP_] = r;
        }
        __syncthreads();
        int nc = offs[GSP_];
        int ncEff = nc < GCAP_ ? nc : GCAP_;
        const unsigned long long* cd = gcand + (size_t)b * GSP_ * CAPSP_;
        for (int i = tid; i < GSP_ * CAPSP_; i += 1024) {
            int s = i >> 9;                      // i / CAPSP_
            int k = i & (CAPSP_ - 1);
            int c0 = offs[s];
            if (k < offs[s + 1] - c0) {
                int d = c0 + k;
                if (d < GCAP_) grp[d] = cd[i];
            }
        }
        __syncthreads();

        // Full-scan exact descending rank (keys unique; LDS broadcast).
        for (int p = tid; p < ncEff; p += 1024) {
            unsigned long long key = grp[p];
            int r = 0;
            for (int q = 0; q < ncEff; ++q)
                r += (grp[q] > key) ? 1 : 0;
            if (r < K_) {
                int o = b * K_ + r;
                unsigned int bits = (unsigned int)(key >> 32);
                float v = __uint_as_float(bits);
                unsigned int idx = 0xFFFFFFFFu - (unsigned int)(key & 0xFFFFFFFFull);
                int y = (int)(idx >> 9), x = (int)(idx & 511u);
                float cx = ((float)x + 0.5f) * 4.0f;
                float cy = ((float)y + 0.5f) * 4.0f;
                float ss = sigmoid_fast(scale[(size_t)b * HW_ + idx]);
                float su = sigmoid_fast(unc  [(size_t)b * HW_ + idx]);
                float side = (32.0f + ss * 480.0f) * (1.0f + 0.25f * su);
                float half = 0.5f * side;
                float x1 = fminf(fmaxf(cx - half, 0.0f), fiw - 1.0f);
                float y1 = fminf(fmaxf(cy - half, 0.0f), fih - 1.0f);
                float x2 = fminf(fmaxf(cx + half, 1.0f), fiw);
                float y2 = fminf(fmaxf(cy + half, 1.0f), fih);
                rois[o * 5 + 0] = (float)b;
                rois[o * 5 + 1] = x1; rois[o * 5 + 2] = y1;
                rois[o * 5 + 3] = x2; rois[o * 5 + 4] = y2;
                scores[o] = v; validf[o] = 1.0f;
            }
        }
        for (int k = nc + tid; k < K_; k += 1024) {
            int o = b * K_ + k;
            rois[o * 5 + 0] = 0.0f; rois[o * 5 + 1] = 0.0f;
            rois[o * 5 + 2] = 0.0f; rois[o * 5 + 3] = 0.0f;
            rois[o * 5 + 4] = 0.0f;
            scores[o] = 0.0f; validf[o] = 0.0f;
        }
        return;
    }

    // ==== Fallback (never taken on sane data): full per-batch recompute ====
    for (int i = tid; i < NBUK_; i += 1024) hist[i] = 0u;
    __syncthreads();
    {
        const float4* rb4 = (const float4*)(route + (size_t)b * HW_);
        const float4* ub4 = (const float4*)(unc_r + (size_t)b * HW_);
        unsigned long long* fbb = fbbuf + (size_t)b * FBCAP_;

        for (int strip = 0; strip < NSTRIP_; ++strip) {
            const int r0 = strip * ROWS_;
            __syncthreads();                    // sm free from previous strip
            for (int slot = tid; slot < 2304; slot += 1024) {
                int row = slot >> 7;
                int gy  = r0 - 1 + row;
                int c4  = slot & 127;
                bool okr = (gy >= 0 && gy < H_);
                int cy  = gy < 0 ? 0 : (gy >= H_ ? H_ - 1 : gy);
                float4 r4 = rb4[cy * 128 + c4];
                float4 u4 = ub4[cy * 128 + c4];
                float4 s;
                s.x = score_ref(r4.x, u4.x);
                s.y = score_ref(r4.y, u4.y);
                s.z = score_ref(r4.z, u4.z);
                s.w = score_ref(r4.w, u4.w);
                if (!okr) { s.x = -INFINITY; s.y = -INFINITY;
                            s.z = -INFINITY; s.w = -INFINITY; }
                *(float4*)&sm[row][c4 * 4] = s;
            }
            __syncthreads();
            for (int g = tid; g < 2048; g += 1024) {
                int ly = 1 + (g >> 7);           // 1..16
                int x0 = (g & 127) * 4;
                int gy = r0 + (ly - 1);
                float4 q0 = *(const float4*)&sm[ly - 1][x0];
                float4 q1 = *(const float4*)&sm[ly    ][x0];
                float4 q2 = *(const float4*)&sm[ly + 1][x0];
                bool hasL = (x0 > 0), hasR = (x0 + 4 < W_);
                float l0 = hasL ? sm[ly - 1][x0 - 1] : -INFINITY;
                float l1 = hasL ? sm[ly    ][x0 - 1] : -INFINITY;
                float l2 = hasL ? sm[ly + 1][x0 - 1] : -INFINITY;
                float e0 = hasR ? sm[ly - 1][x0 + 4] : -INFINITY;
                float e1 = hasR ? sm[ly    ][x0 + 4] : -INFINITY;
                float e2 = hasR ? sm[ly + 1][x0 + 4] : -INFINITY;
                float f_m1 = fmaxf(l0, fmaxf(l1, l2));
                float f_0  = fmaxf(q0.x, fmaxf(q1.x, q2.x));
                float f_1  = fmaxf(q0.y, fmaxf(q1.y, q2.y));
                float f_2  = fmaxf(q0.z, fmaxf(q1.z, q2.z));
                float f_3  = fmaxf(q0.w, fmaxf(q1.w, q2.w));
                float f_4  = fmaxf(e0, fmaxf(e1, e2));
                float tb0  = fmaxf(q0.x, q2.x);
                float tb1  = fmaxf(q0.y, q2.y);
                float tb2  = fmaxf(q0.z, q2.z);
                float tb3  = fmaxf(q0.w, q2.w);
                float vv[4] = { q1.x, q1.y, q1.z, q1.w };
                float mm[4];
                mm[0] = fmaxf(fmaxf(f_m1, f_1), tb0);
                mm[1] = fmaxf(fmaxf(f_0,  f_2), tb1);
                mm[2] = fmaxf(fmaxf(f_1,  f_3), tb2);
                mm[3] = fmaxf(fmaxf(f_2,  f_4), tb3);
                #pragma unroll
                for (int i = 0; i < 4; ++i) {
                    if (vv[i] >= mm[i]) {
                        unsigned int bits = __float_as_uint(vv[i]);
                        unsigned int idx  = (unsigned int)(gy * W_ + x0 + i);
                        int p = atomicAdd(&sh_fn, 1);
                        if (p < FBCAP_) {
                            fbb[p] = ((unsigned long long)bits << 32)
                                     | (0xFFFFFFFFu - idx);
                            atomicAdd(&hist[bits >> 18], 1u);
                        }
                    }
                }
            }
        }
        __syncthreads();                        // sm dead; hist complete

        if (wid == 0) {
            int Tv = 0;
            int total = 0;
            for (int c = NBUK_ / 64 - 1; c >= 0; --c) {
                int cnt = (int)hist[c * 64 + lane];
                int sum = cnt;
                #pragma unroll
                for (int off = 32; off > 0; off >>= 1)
                    sum += __shfl_down(sum, off, 64);
                sum = __shfl(sum, 0, 64);
                if (total + sum < K_) { total += sum; continue; }
                int suf = cnt;
                #pragma unroll
                for (int off = 1; off < 64; off <<= 1) {
                    int o = __shfl_down(suf, off, 64);
                    suf += (lane + off < 64) ? o : 0;
                }
                bool cond = (total + suf) >= K_;
                unsigned long long mask = __ballot(cond);
                int ls = 63 - __builtin_clzll(mask);
                Tv = c * 64 + ls;
                break;
            }
            if (Tv < 1) Tv = 1;
            int run = 0;
            for (int cb = NBUK_ - 64; cb >= (Tv & ~63); cb -= 64) {
                int beta = cb + lane;
                int cnt = (beta >= Tv) ? (int)hist[beta] : 0;
                int suf = cnt;
                #pragma unroll
                for (int off = 1; off < 64; off <<= 1) {
                    int o = __shfl_down(suf, off, 64);
                    suf += (lane + off < 64) ? o : 0;
                }
                int chunk_total = __shfl(suf, 0, 64);
                if (beta >= Tv) cursor[beta] = (unsigned int)(run + (suf - cnt));
                run += chunk_total;
            }
            if (lane == 0) { sh_T = Tv; sh_nc = run; }
        }
        __syncthreads();

        const unsigned int T = (unsigned int)sh_T;
        const unsigned long long* fbbr = fbbuf + (size_t)b * FBCAP_;
        int n = sh_fn; if (n > FBCAP_) n = FBCAP_;
        for (int i = tid; i < n; i += 1024) {
            unsigned long long k = fbbr[i];
            unsigned int b0 = (unsigned int)(k >> 50);
            if (b0 >= T) {
                unsigned int pos = atomicAdd(&cursor[b0], 1u);
                if (pos < GCAP_) grp[pos] = k;
            }
        }
        __syncthreads();

        int nc = sh_nc;
        int ncEff = nc < GCAP_ ? nc : GCAP_;
        for (int p = tid; p < ncEff; p += 1024) {
            unsigned long long key = grp[p];
            unsigned int beta = (unsigned int)(key >> 50);
            int segEnd   = (int)cursor[beta];
            int segStart = segEnd - (int)hist[beta];
            int qEnd = segEnd < GCAP_ ? segEnd : GCAP_;
            int r = 0;
            for (int q = segStart; q < qEnd; ++q)
                r += (grp[q] > key) ? 1 : 0;
            int rank = segStart + r;
            if (rank < K_) {
                int o = b * K_ + rank;
                unsigned int bits = (unsigned int)(key >> 32);
                float v = __uint_as_float(bits);
                unsigned int idx = 0xFFFFFFFFu - (unsigned int)(key & 0xFFFFFFFFull);
                int y = (int)(idx >> 9), x = (int)(idx & 511u);
                float cx = ((float)x + 0.5f) * 4.0f;
                float cy = ((float)y + 0.5f) * 4.0f;
                float ss = sigmoid_fast(scale[(size_t)b * HW_ + idx]);
                float su = sigmoid_fast(unc  [(size_t)b * HW_ + idx]);
                float side = (32.0f + ss * 480.0f) * (1.0f + 0.25f * su);
                float half = 0.5f * side;
                float x1 = fminf(fmaxf(cx - half, 0.0f), fiw - 1.0f);
                float y1 = fminf(fmaxf(cy - half, 0.0f), fih - 1.0f);
                float x2 = fminf(fmaxf(cx + half, 1.0f), fiw);
                float y2 = fminf(fmaxf(cy + half, 1.0f), fih);
                rois[o * 5 + 0] = (float)b;
                rois[o * 5 + 1] = x1; rois[o * 5 + 2] = y1;
                rois[o * 5 + 3] = x2; rois[o * 5 + 4] = y2;
                scores[o] = v; validf[o] = 1.0f;
            }
        }
        for (int k = sh_nc + tid; k < K_; k += 1024) {
            int o = b * K_ + k;
            rois[o * 5 + 0] = 0.0f; rois[o * 5 + 1] = 0.0f;
            rois[o * 5 + 2] = 0.0f; rois[o * 5 + 3] = 0.0f;
            rois[o * 5 + 4] = 0.0f;
            scores[o] = 0.0f; validf[o] = 0.0f;
        }
    }
}

extern "C" void kernel_launch(void* const* d_in, const int* in_sizes, int n_in,
                              void* d_out, int out_size, void* d_ws, size_t ws_size,
                              hipStream_t stream) {
    const float* route = (const float*)d_in[0];
    const float* scale = (const float*)d_in[1];
    const float* unc   = (const float*)d_in[2];
    const int*   ih    = (const int*)d_in[3];
    const int*   iw    = (const int*)d_in[4];
    float* out = (float*)d_out;

    // ws layout:
    //   hotlist  8,388,608 B (32 x 256 x 128 u64)  — per-wave hot segments
    //   hcnt8       32,768 B (32 x 256 i32)        — exact per-wave counts
    //   ghist      262,144 B (32 x 2048 u32)       — fine hist (memset 0)
    //   gncnt        1,024 B (32 x 8 i32)          — per-split counts
    //   gcand    1,048,576 B (32 x 8 x 512 u64)    — counted prefixes only
    //   fbbuf   11,534,336 B (32 x 45056 u64)      — fallback only
    unsigned char* base = (unsigned char*)d_ws;
    unsigned long long* hotlist = (unsigned long long*)base;
    int* hcnt8          = (int*)(base + HL_BYTES_);
    unsigned int* ghist = (unsigned int*)(base + HL_BYTES_ + HC_BYTES_);
    int* gncnt          = (int*)(base + HL_BYTES_ + HC_BYTES_ + GH_BYTES_);
    unsigned long long* gcand =
        (unsigned long long*)(base + HL_BYTES_ + HC_BYTES_ + GH_BYTES_ + GN_BYTES_);
    unsigned long long* fbbuf =
        (unsigned long long*)(base + HL_BYTES_ + HC_BYTES_ + GH_BYTES_ + GN_BYTES_ + GC_BYTES_);

    hipMemsetAsync(ghist, 0, GH_BYTES_, stream);

    dim3 g(NSTRIP_, B_);      // 32 strips x 32 batches
    fused_peak_kernel<<<g, THR_, 0, stream>>>(route, unc, hotlist, hcnt8);
    dim3 gs(GSP_, B_);        // 8 splits x 32 batches
    hist_kernel<<<gs, 512, 0, stream>>>(hotlist, hcnt8, ghist);
    scatter_kernel<<<gs, 512, 0, stream>>>(hotlist, hcnt8, ghist,
                                           gcand, gncnt);
    rank_emit_kernel<<<B_, 1024, 0, stream>>>(route, unc, scale, unc,
                                              ghist, gcand, gncnt, fbbuf,
                                              ih, iw, out);
}

// Round 12
// 159.035 us; speedup vs baseline: 1.0809x; 1.0809x over previous
//
#include <hip/hip_runtime.h>
#include <hip/hip_bf16.h>
#include <math.h>

// H2R detector: score map -> 3x3 NMS peaks -> per-batch top-1000 -> ROIs.
// [B=32,1,512,512] fp32 inputs; out = rois[32,1000,5] ++ scores[32,1000]
// ++ valid[32,1000] = 224000 floats.
//
// Scoring replicates numpy's SIMD (Cephes) fp32 expf op-for-op (verified
// bit-exact rounds 5-10: absmax 0.0). DO NOT alter score or emit paths.
//
// Round 23: RESTORE of the session-best configuration (round-16 comment
// version, measured 158.6us). Post-R5 variants all regressed: exact
// prefixes (163.4), per-wave segs (172.7), fine-bucket rank (167.6),
// 4-dispatch split (171.9). The winning property is select2's UNIFORM
// DENSE zero-padded stream (fixed loop bounds, ulonglong2 loads, no
// dependent per-segment counts) — prefetch-friendly in a latency-bound
// kernel. Structure:
//   - fused_peak: score strip + 3x3 NMS; hot peaks (score >= 0.5) appended
//     per-strip via ballot-aggregated LDS counter; zero-filled tails;
//     64-bucket window hist (256 B plain stores).
//   - select2: window-hist sum (8 KB) -> T within top-64 buckets ->
//     stream full hot region (224 KB, unconditional) -> cursor scatter ->
//     segment rank (exact 64-bit keys = full desc-sort order) -> emit.
//   - fallback (window < K; never taken): self-contained per-batch
//     recompute inside select2.

#define B_   32
#define H_   512
#define W_   512
#define HW_  (H_ * W_)
#define K_   1000
#define ROWS_ 16            // interior rows per strip
#define THR_  512           // threads per fused block (8 waves)
#define NSTRIP_ 32          // H_/ROWS_
#define NBUK_ 4096          // score buckets = bits >> 18 (score < 1.0)
#define GCAP_ 2048          // grouped-candidate LDS capacity (nc ~ 1000-1150)
#define HOTCAP_ 896         // per-strip hot-list capacity (mean ~420-560)
#define HOTPAIR_ (NSTRIP_ * HOTCAP_ / 2)   // 14336 pairs per batch
#define HOTBITS_ 0x3F000000u               // fp32 bits of 0.5f (bucket 4032)
#define WBASE_ (NBUK_ - 64)                // 4032: window base bucket
#define FBCAP_ 45056                       // fallback per-batch peak capacity

#define HL_BYTES_  ((size_t)B_ * NSTRIP_ * HOTCAP_ * 8)   // 7,340,032
#define GW_BYTES_  ((size_t)B_ * NSTRIP_ * 64 * 4)        // 262,144

// ---- numpy SIMD (Cephes) fp32 exp replica — bit-exact, do not touch -------
__device__ __forceinline__ float np_expf(float x) {
#pragma clang fp contract(off)
    const float log2e = 1.44269504088896341f;
    float z = x * log2e;
    float m = rintf(z);
    float r = fmaf(m, -0.693359375f, x);
    r = fmaf(m, 2.12194440e-4f, r);
    float r2 = r * r;
    float p = fmaf(1.9875691500e-4f, r, 1.3981999507e-3f);
    p = fmaf(p, r, 8.3334519073e-3f);
    p = fmaf(p, r, 4.1665795894e-2f);
    p = fmaf(p, r, 1.6666665459e-1f);
    p = fmaf(p, r, 5.0000001201e-1f);
    p = fmaf(p, r2, r);
    p = p + 1.0f;
    int mi = (int)m;
    float sc = __int_as_float((127 + mi) << 23);
    return p * sc;
}

__device__ __forceinline__ float sigmoid_np(float x) {
#pragma clang fp contract(off)
    float e = np_expf(-x);
    float d = 1.0f + e;
    return 1.0f / d;
}

__device__ __forceinline__ float score_ref(float r, float u) {
#pragma clang fp contract(off)
    float s  = sigmoid_np(r);
    float s2 = s * s;
    float su = sigmoid_np(u);
    float t  = 0.35f * su;
    float m  = 1.0f - t;
    return s2 * m;
}

__device__ __forceinline__ float sigmoid_fast(float x) {  // box geometry only
    return 1.0f / (1.0f + __expf(-x));
}

// ---- Fused: score strip + 3x3 peak test -> hot list + window hist ---------
__global__ __launch_bounds__(THR_, 4) void fused_peak_kernel(
    const float* __restrict__ route, const float* __restrict__ unc,
    unsigned long long* __restrict__ hotlist,
    unsigned int* __restrict__ ghw)
{
    __shared__ float sm[ROWS_ + 2][W_];          // 18x512 = 36.9 KB
    __shared__ unsigned int whist[64];
    __shared__ int hcnt;

    const int tid   = threadIdx.x;
    const int lane  = tid & 63;
    const int strip = blockIdx.x;                // 0..31
    const int b     = blockIdx.y;                // 0..31
    const int r0    = strip * ROWS_;
    if (tid < 64) whist[tid] = 0u;
    if (tid == 0) hcnt = 0;

    const float4* rb4 = (const float4*)(route + (size_t)b * HW_);
    const float4* ub4 = (const float4*)(unc   + (size_t)b * HW_);
    unsigned long long* hseg =
        hotlist + (size_t)(b * NSTRIP_ + strip) * HOTCAP_;

    // Stage 18 halo rows: branchless (slot clamp), 10 loads in flight.
    float4 rv[5], uv[5];
    int lrow[5], c4[5]; bool ok[5];
    #pragma unroll
    for (int k = 0; k < 5; ++k) {
        int slot = tid + k * THR_;
        slot = slot < 2303 ? slot : 2303;
        int row = slot >> 7;
        int gy  = r0 - 1 + row;
        lrow[k] = row; c4[k] = slot & 127;
        ok[k]   = (gy >= 0 && gy < H_);
        int cy  = gy < 0 ? 0 : (gy >= H_ ? H_ - 1 : gy);
        rv[k] = rb4[cy * 128 + c4[k]];
        uv[k] = ub4[cy * 128 + c4[k]];
    }
    #pragma unroll
    for (int k = 0; k < 5; ++k) {
        float4 s;
        s.x = score_ref(rv[k].x, uv[k].x);
        s.y = score_ref(rv[k].y, uv[k].y);
        s.z = score_ref(rv[k].z, uv[k].z);
        s.w = score_ref(rv[k].w, uv[k].w);
        if (!ok[k]) { s.x = -INFINITY; s.y = -INFINITY;
                      s.z = -INFINITY; s.w = -INFINITY; }
        *(float4*)&sm[lrow[k]][c4[k] * 4] = s;
    }
    __syncthreads();

    // Peak test: 16x512 interior, 4-px groups, float4 reads + column max.
    // Only hot peaks (bits >= 0.5f) are emitted: ballot-aggregated append.
    const unsigned long long lt = (1ull << lane) - 1ull;
    #pragma unroll
    for (int j = 0; j < 4; ++j) {
        int g  = tid + j * THR_;                 // 0..2047
        int ly = 1 + (g >> 7);                   // 1..16
        int x0 = (g & 127) * 4;
        int gy = r0 + (ly - 1);
        float4 q0 = *(const float4*)&sm[ly - 1][x0];
        float4 q1 = *(const float4*)&sm[ly    ][x0];
        float4 q2 = *(const float4*)&sm[ly + 1][x0];
        bool hasL = (x0 > 0), hasR = (x0 + 4 < W_);
        float l0 = hasL ? sm[ly - 1][x0 - 1] : -INFINITY;
        float l1 = hasL ? sm[ly    ][x0 - 1] : -INFINITY;
        float l2 = hasL ? sm[ly + 1][x0 - 1] : -INFINITY;
        float e0 = hasR ? sm[ly - 1][x0 + 4] : -INFINITY;
        float e1 = hasR ? sm[ly    ][x0 + 4] : -INFINITY;
        float e2 = hasR ? sm[ly + 1][x0 + 4] : -INFINITY;
        float f_m1 = fmaxf(l0, fmaxf(l1, l2));
        float f_0  = fmaxf(q0.x, fmaxf(q1.x, q2.x));
        float f_1  = fmaxf(q0.y, fmaxf(q1.y, q2.y));
        float f_2  = fmaxf(q0.z, fmaxf(q1.z, q2.z));
        float f_3  = fmaxf(q0.w, fmaxf(q1.w, q2.w));
        float f_4  = fmaxf(e0, fmaxf(e1, e2));
        float tb0  = fmaxf(q0.x, q2.x);
        float tb1  = fmaxf(q0.y, q2.y);
        float tb2  = fmaxf(q0.z, q2.z);
        float tb3  = fmaxf(q0.w, q2.w);
        float vv[4] = { q1.x, q1.y, q1.z, q1.w };
        float mm[4];
        mm[0] = fmaxf(fmaxf(f_m1, f_1), tb0);
        mm[1] = fmaxf(fmaxf(f_0,  f_2), tb1);
        mm[2] = fmaxf(fmaxf(f_1,  f_3), tb2);
        mm[3] = fmaxf(fmaxf(f_2,  f_4), tb3);
        #pragma unroll
        for (int i = 0; i < 4; ++i) {
            bool take = (vv[i] >= mm[i]);
            unsigned int bits = __float_as_uint(vv[i]);
            bool hot = take && (bits >= HOTBITS_);
            unsigned long long hmk = __ballot(hot);
            if (hmk) {
                int ldr = __ffsll(hmk) - 1;
                int hb = 0;
                if (lane == ldr) hb = atomicAdd(&hcnt, __popcll(hmk));
                hb = __shfl(hb, ldr, 64);
                if (hot) {
                    int hp = hb + __popcll(hmk & lt);
                    if (hp < HOTCAP_) {
                        unsigned int idx = (unsigned int)(gy * W_ + x0 + i);
                        hseg[hp] = ((unsigned long long)bits << 32)
                                   | (0xFFFFFFFFu - idx);
                        atomicAdd(&whist[(bits >> 18) - WBASE_], 1u);
                    }
                }
            }
        }
    }
    __syncthreads();

    // Zero-fill the hot-list tail (select2 streams it unconditionally).
    {
        int hn = hcnt < HOTCAP_ ? hcnt : HOTCAP_;
        for (int i = hn + tid; i < HOTCAP_; i += THR_) hseg[i] = 0ull;
    }
    // Plain coalesced store of this strip's 64-bucket window hist.
    if (tid < 64)
        ghw[(size_t)(b * NSTRIP_ + strip) * 64 + tid] = whist[tid];
}

// ---- select2: window hist -> T -> hot stream -> rank -> emit --------------
// LDS overlay: u_ holds sm[18][512] during the fallback strip loop, then
// cursor[4096] + grp[2048] afterwards (fast path uses only the latter).
__global__ __launch_bounds__(1024) void select2_kernel(
    const float* __restrict__ route, const float* __restrict__ unc_r,
    const float* __restrict__ scale, const float* __restrict__ unc,
    const unsigned long long* __restrict__ hotlist,
    const unsigned int* __restrict__ ghw,
    unsigned long long* __restrict__ fbbuf,
    const int* __restrict__ ih_p, const int* __restrict__ iw_p,
    float* __restrict__ out)
{
    __shared__ __align__(16) unsigned char u_[(ROWS_ + 2) * W_ * 4]; // 36.9 KB
    __shared__ unsigned int hist[NBUK_];                             // 16 KB
    __shared__ int sh_T, sh_nc, sh_fb, sh_fn;

    float (*sm)[W_] = (float (*)[W_])u_;
    unsigned int* cursor = (unsigned int*)u_;                        // 16 KB
    unsigned long long* grp = (unsigned long long*)(u_ + 16384);     // 16 KB

    const int b = blockIdx.x, tid = threadIdx.x;
    const int lane = tid & 63, wid = tid >> 6;
    const unsigned int* gbase = ghw + (size_t)b * NSTRIP_ * 64;

    // Phase A (fast): sum 32 per-strip window hists (8 KB read).
    if (tid == 0) { sh_fb = 0; sh_T = 1; sh_nc = 0; sh_fn = 0; }
    if (tid < 64) hist[WBASE_ + tid] = 0u;
    __syncthreads();
    {
        for (int i = tid; i < NSTRIP_ * 64; i += 1024) {
            unsigned int v = gbase[i];
            if (v) atomicAdd(&hist[WBASE_ + (i & 63)], v);
        }
    }
    __syncthreads();

    // Phase B (fast, wave0): T within the window, else flag fallback.
    if (wid == 0) {
        int cnt = (int)hist[WBASE_ + lane];
        int sum = cnt;
        #pragma unroll
        for (int off = 32; off > 0; off >>= 1)
            sum += __shfl_down(sum, off, 64);
        sum = __shfl(sum, 0, 64);
        if (sum < K_) {
            if (lane == 0) sh_fb = 1;
        } else {
            int suf = cnt;                       // inclusive suffix over lanes
            #pragma unroll
            for (int off = 1; off < 64; off <<= 1) {
                int o = __shfl_down(suf, off, 64);
                suf += (lane + off < 64) ? o : 0;
            }
            bool cond = suf >= K_;
            unsigned long long mask = __ballot(cond);
            int ls = 63 - __builtin_clzll(mask);
            if (lane >= ls) cursor[WBASE_ + lane] = (unsigned int)(suf - cnt);
            int ncv = __shfl(suf, ls, 64);
            if (lane == 0) { sh_T = WBASE_ + ls; sh_nc = ncv; }
        }
    }
    __syncthreads();
    const int fb = sh_fb;

    if (fb) {
        // ==== Fallback (never taken on sane data): full per-batch recompute.
        for (int i = tid; i < NBUK_; i += 1024) hist[i] = 0u;
        __syncthreads();

        const float4* rb4 = (const float4*)(route + (size_t)b * HW_);
        const float4* ub4 = (const float4*)(unc_r + (size_t)b * HW_);
        unsigned long long* fbb = fbbuf + (size_t)b * FBCAP_;

        for (int strip = 0; strip < NSTRIP_; ++strip) {
            const int r0 = strip * ROWS_;
            __syncthreads();                    // sm free from previous strip
            for (int slot = tid; slot < 2304; slot += 1024) {
                int row = slot >> 7;
                int gy  = r0 - 1 + row;
                int c4  = slot & 127;
                bool okr = (gy >= 0 && gy < H_);
                int cy  = gy < 0 ? 0 : (gy >= H_ ? H_ - 1 : gy);
                float4 r4 = rb4[cy * 128 + c4];
                float4 u4 = ub4[cy * 128 + c4];
                float4 s;
                s.x = score_ref(r4.x, u4.x);
                s.y = score_ref(r4.y, u4.y);
                s.z = score_ref(r4.z, u4.z);
                s.w = score_ref(r4.w, u4.w);
                if (!okr) { s.x = -INFINITY; s.y = -INFINITY;
                            s.z = -INFINITY; s.w = -INFINITY; }
                *(float4*)&sm[row][c4 * 4] = s;
            }
            __syncthreads();
            // Peak test over the 16x512 interior (4-px groups).
            for (int g = tid; g < 2048; g += 1024) {
                int ly = 1 + (g >> 7);           // 1..16
                int x0 = (g & 127) * 4;
                int gy = r0 + (ly - 1);
                float4 q0 = *(const float4*)&sm[ly - 1][x0];
                float4 q1 = *(const float4*)&sm[ly    ][x0];
                float4 q2 = *(const float4*)&sm[ly + 1][x0];
                bool hasL = (x0 > 0), hasR = (x0 + 4 < W_);
                float l0 = hasL ? sm[ly - 1][x0 - 1] : -INFINITY;
                float l1 = hasL ? sm[ly    ][x0 - 1] : -INFINITY;
                float l2 = hasL ? sm[ly + 1][x0 - 1] : -INFINITY;
                float e0 = hasR ? sm[ly - 1][x0 + 4] : -INFINITY;
                float e1 = hasR ? sm[ly    ][x0 + 4] : -INFINITY;
                float e2 = hasR ? sm[ly + 1][x0 + 4] : -INFINITY;
                float f_m1 = fmaxf(l0, fmaxf(l1, l2));
                float f_0  = fmaxf(q0.x, fmaxf(q1.x, q2.x));
                float f_1  = fmaxf(q0.y, fmaxf(q1.y, q2.y));
                float f_2  = fmaxf(q0.z, fmaxf(q1.z, q2.z));
                float f_3  = fmaxf(q0.w, fmaxf(q1.w, q2.w));
                float f_4  = fmaxf(e0, fmaxf(e1, e2));
                float tb0  = fmaxf(q0.x, q2.x);
                float tb1  = fmaxf(q0.y, q2.y);
                float tb2  = fmaxf(q0.z, q2.z);
                float tb3  = fmaxf(q0.w, q2.w);
                float vv[4] = { q1.x, q1.y, q1.z, q1.w };
                float mm[4];
                mm[0] = fmaxf(fmaxf(f_m1, f_1), tb0);
                mm[1] = fmaxf(fmaxf(f_0,  f_2), tb1);
                mm[2] = fmaxf(fmaxf(f_1,  f_3), tb2);
                mm[3] = fmaxf(fmaxf(f_2,  f_4), tb3);
                #pragma unroll
                for (int i = 0; i < 4; ++i) {
                    if (vv[i] >= mm[i]) {
                        unsigned int bits = __float_as_uint(vv[i]);
                        unsigned int idx  = (unsigned int)(gy * W_ + x0 + i);
                        int p = atomicAdd(&sh_fn, 1);
                        if (p < FBCAP_) {
                            fbb[p] = ((unsigned long long)bits << 32)
                                     | (0xFFFFFFFFu - idx);
                            atomicAdd(&hist[bits >> 18], 1u);
                        }
                    }
                }
            }
        }
        __syncthreads();                        // sm dead; hist complete

        // Full T-scan + cursor suffix-init (wave0).
        if (wid == 0) {
            int Tv = 0;
            int total = 0;
            for (int c = NBUK_ / 64 - 1; c >= 0; --c) {
                int cnt = (int)hist[c * 64 + lane];
                int sum = cnt;
                #pragma unroll
                for (int off = 32; off > 0; off >>= 1)
                    sum += __shfl_down(sum, off, 64);
                sum = __shfl(sum, 0, 64);
                if (total + sum < K_) { total += sum; continue; }
                int suf = cnt;
                #pragma unroll
                for (int off = 1; off < 64; off <<= 1) {
                    int o = __shfl_down(suf, off, 64);
                    suf += (lane + off < 64) ? o : 0;
                }
                bool cond = (total + suf) >= K_;
                unsigned long long mask = __ballot(cond);
                int ls = 63 - __builtin_clzll(mask);
                Tv = c * 64 + ls;
                break;
            }
            if (Tv < 1) Tv = 1;
            int run = 0;
            for (int cb = NBUK_ - 64; cb >= (Tv & ~63); cb -= 64) {
                int beta = cb + lane;
                int cnt = (beta >= Tv) ? (int)hist[beta] : 0;
                int suf = cnt;
                #pragma unroll
                for (int off = 1; off < 64; off <<= 1) {
                    int o = __shfl_down(suf, off, 64);
                    suf += (lane + off < 64) ? o : 0;
                }
                int chunk_total = __shfl(suf, 0, 64);
                if (beta >= Tv) cursor[beta] = (unsigned int)(run + (suf - cnt));
                run += chunk_total;
            }
            if (lane == 0) { sh_T = Tv; sh_nc = run; }
        }
    }
    __syncthreads();
    const unsigned int T = (unsigned int)sh_T;

    // Phase C: stream (hot list | fallback buffer) and scatter grouped.
    if (!fb) {
        const ulonglong2* src =
            (const ulonglong2*)(hotlist + (size_t)b * NSTRIP_ * HOTCAP_);
        for (int i = tid; i < HOTPAIR_; i += 1024) {
            ulonglong2 a = src[i];
            unsigned int b0 = (unsigned int)(a.x >> 50);
            unsigned int b1 = (unsigned int)(a.y >> 50);
            if (b0 >= T) {
                unsigned int pos = atomicAdd(&cursor[b0], 1u);
                if (pos < GCAP_) grp[pos] = a.x;
            }
            if (b1 >= T) {
                unsigned int pos = atomicAdd(&cursor[b1], 1u);
                if (pos < GCAP_) grp[pos] = a.y;
            }
        }
    } else {
        const unsigned long long* fbb = fbbuf + (size_t)b * FBCAP_;
        int n = sh_fn; if (n > FBCAP_) n = FBCAP_;
        for (int i = tid; i < n; i += 1024) {
            unsigned long long k = fbb[i];
            unsigned int b0 = (unsigned int)(k >> 50);
            if (b0 >= T) {
                unsigned int pos = atomicAdd(&cursor[b0], 1u);
                if (pos < GCAP_) grp[pos] = k;
            }
        }
    }
    __syncthreads();

    // Phase D: exact descending rank per candidate + direct emit.
    // rank = (#elements in higher buckets) + (#same-bucket keys > mine).
    // Keys unique (idx in low bits) -> identical order to a full desc sort.
    const float fih = (float)(*ih_p);
    const float fiw = (float)(*iw_p);
    float* rois   = out;                       // [B,K,5]
    float* scores = out + (size_t)B_ * K_ * 5; // [B,K]
    float* validf = out + (size_t)B_ * K_ * 6; // [B,K]

    int nc = sh_nc;
    int ncEff = nc < GCAP_ ? nc : GCAP_;
    for (int p = tid; p < ncEff; p += 1024) {
        unsigned long long key = grp[p];
        unsigned int beta = (unsigned int)(key >> 50);
        int segEnd   = (int)cursor[beta];         // start + cnt
        int segStart = segEnd - (int)hist[beta];
        int qEnd = segEnd < GCAP_ ? segEnd : GCAP_;
        int r = 0;
        for (int q = segStart; q < qEnd; ++q)
            r += (grp[q] > key) ? 1 : 0;
        int rank = segStart + r;
        if (rank < K_) {
            int o = b * K_ + rank;
            unsigned int bits = (unsigned int)(key >> 32);
            float v = __uint_as_float(bits);
            unsigned int idx = 0xFFFFFFFFu - (unsigned int)(key & 0xFFFFFFFFull);
            int y = (int)(idx >> 9), x = (int)(idx & 511u);
            float cx = ((float)x + 0.5f) * 4.0f;
            float cy = ((float)y + 0.5f) * 4.0f;
            float ss = sigmoid_fast(scale[(size_t)b * HW_ + idx]);
            float su = sigmoid_fast(unc  [(size_t)b * HW_ + idx]);
            float side = (32.0f + ss * 480.0f) * (1.0f + 0.25f * su);
            float half = 0.5f * side;
            float x1 = fminf(fmaxf(cx - half, 0.0f), fiw - 1.0f);
            float y1 = fminf(fmaxf(cy - half, 0.0f), fih - 1.0f);
            float x2 = fminf(fmaxf(cx + half, 1.0f), fiw);
            float y2 = fminf(fmaxf(cy + half, 1.0f), fih);
            rois[o * 5 + 0] = (float)b;
            rois[o * 5 + 1] = x1; rois[o * 5 + 2] = y1;
            rois[o * 5 + 3] = x2; rois[o * 5 + 4] = y2;
            scores[o] = v; validf[o] = 1.0f;
        }
    }
    // Tail fill (only if fewer than K candidates exist — normally empty).
    for (int k = nc + tid; k < K_; k += 1024) {
        int o = b * K_ + k;
        rois[o * 5 + 0] = 0.0f; rois[o * 5 + 1] = 0.0f;
        rois[o * 5 + 2] = 0.0f; rois[o * 5 + 3] = 0.0f;
        rois[o * 5 + 4] = 0.0f;
        scores[o] = 0.0f; validf[o] = 0.0f;
    }
}

extern "C" void kernel_launch(void* const* d_in, const int* in_sizes, int n_in,
                              void* d_out, int out_size, void* d_ws, size_t ws_size,
                              hipStream_t stream) {
    const float* route = (const float*)d_in[0];
    const float* scale = (const float*)d_in[1];
    const float* unc   = (const float*)d_in[2];
    const int*   ih    = (const int*)d_in[3];
    const int*   iw    = (const int*)d_in[4];
    float* out = (float*)d_out;

    // ws layout (all fast-path regions fully rewritten each launch):
    //   hotlist  7,340,032 B (32 x 32 x 896 x u64)  — fast-path stream
    //   ghw        262,144 B (32 x 32 x 64 x u32)   — window hists
    //   fbbuf   11,534,336 B (32 x 45056 x u64)     — fallback only
    unsigned char* base = (unsigned char*)d_ws;
    unsigned long long* hotlist = (unsigned long long*)base;
    unsigned int* ghw = (unsigned int*)(base + HL_BYTES_);
    unsigned long long* fbbuf =
        (unsigned long long*)(base + HL_BYTES_ + GW_BYTES_);

    dim3 g(NSTRIP_, B_);      // 32 strips x 32 batches
    fused_peak_kernel<<<g, THR_, 0, stream>>>(route, unc, hotlist, ghw);
    select2_kernel<<<B_, 1024, 0, stream>>>(route, unc, scale, unc,
                                            hotlist, ghw, fbbuf,
                                            ih, iw, out);
}

// Round 13
// 157.142 us; speedup vs baseline: 1.0940x; 1.0120x over previous
//
#include <hip/hip_runtime.h>
#include <hip/hip_bf16.h>
#include <math.h>

// H2R detector: score map -> 3x3 NMS peaks -> per-batch top-1000 -> ROIs.
// [B=32,1,512,512] fp32 inputs; out = rois[32,1000,5] ++ scores[32,1000]
// ++ valid[32,1000] = 224000 floats.
//
// Scoring replicates numpy's SIMD (Cephes) fp32 expf op-for-op (verified
// bit-exact rounds 5-10: absmax 0.0). DO NOT alter score or emit paths.
//
// Round 24: R23 (=session-best structure, 159.0us) + ONE isolated delta:
// fused_peak's hot-append switches from {leader LDS-atomic + shfl
// broadcast} x16 per thread-group to per-WAVE register ballot counters
// (R9-proven), writing 8 x 128-slot sub-segments per strip; each wave
// zero-fills its own tail. select2 is BYTE-IDENTICAL to R23's (uniform
// dense zero-padded ulonglong2 stream — the property that made R5/R23
// fastest). Region 896 -> 1024 slots/strip (+14% stream bytes, minor).
// Key set, window hist, T, rank, emit: bit-identical; within-region order
// differs but rank is order-independent (exact 64-bit keys).
// Decision rule: <157 keep; >=159 -> declare floor next round.

#define B_   32
#define H_   512
#define W_   512
#define HW_  (H_ * W_)
#define K_   1000
#define ROWS_ 16            // interior rows per strip
#define THR_  512           // threads per fused block (8 waves)
#define NSTRIP_ 32          // H_/ROWS_
#define NBUK_ 4096          // score buckets = bits >> 18 (score < 1.0)
#define GCAP_ 2048          // grouped-candidate LDS capacity (nc ~ 1000-1150)
#define HSEG_ 128           // per-wave hot capacity (mean ~55, ~10 sigma)
#define HOTCAP_ (8 * HSEG_)                // 1024 slots per strip
#define HOTPAIR_ (NSTRIP_ * HOTCAP_ / 2)   // 16384 pairs per batch
#define HOTBITS_ 0x3F000000u               // fp32 bits of 0.5f (bucket 4032)
#define WBASE_ (NBUK_ - 64)                // 4032: window base bucket
#define FBCAP_ 45056                       // fallback per-batch peak capacity

#define HL_BYTES_  ((size_t)B_ * NSTRIP_ * HOTCAP_ * 8)   // 8,388,608
#define GW_BYTES_  ((size_t)B_ * NSTRIP_ * 64 * 4)        // 262,144

// ---- numpy SIMD (Cephes) fp32 exp replica — bit-exact, do not touch -------
__device__ __forceinline__ float np_expf(float x) {
#pragma clang fp contract(off)
    const float log2e = 1.44269504088896341f;
    float z = x * log2e;
    float m = rintf(z);
    float r = fmaf(m, -0.693359375f, x);
    r = fmaf(m, 2.12194440e-4f, r);
    float r2 = r * r;
    float p = fmaf(1.9875691500e-4f, r, 1.3981999507e-3f);
    p = fmaf(p, r, 8.3334519073e-3f);
    p = fmaf(p, r, 4.1665795894e-2f);
    p = fmaf(p, r, 1.6666665459e-1f);
    p = fmaf(p, r, 5.0000001201e-1f);
    p = fmaf(p, r2, r);
    p = p + 1.0f;
    int mi = (int)m;
    float sc = __int_as_float((127 + mi) << 23);
    return p * sc;
}

__device__ __forceinline__ float sigmoid_np(float x) {
#pragma clang fp contract(off)
    float e = np_expf(-x);
    float d = 1.0f + e;
    return 1.0f / d;
}

__device__ __forceinline__ float score_ref(float r, float u) {
#pragma clang fp contract(off)
    float s  = sigmoid_np(r);
    float s2 = s * s;
    float su = sigmoid_np(u);
    float t  = 0.35f * su;
    float m  = 1.0f - t;
    return s2 * m;
}

__device__ __forceinline__ float sigmoid_fast(float x) {  // box geometry only
    return 1.0f / (1.0f + __expf(-x));
}

// ---- Fused: score strip + 3x3 peak test -> per-wave hot segs + hist -------
__global__ __launch_bounds__(THR_, 4) void fused_peak_kernel(
    const float* __restrict__ route, const float* __restrict__ unc,
    unsigned long long* __restrict__ hotlist,
    unsigned int* __restrict__ ghw)
{
    __shared__ float sm[ROWS_ + 2][W_];          // 18x512 = 36.9 KB
    __shared__ unsigned int whist[64];

    const int tid   = threadIdx.x;
    const int lane  = tid & 63;
    const int wid   = tid >> 6;                  // 0..7
    const int strip = blockIdx.x;                // 0..31
    const int b     = blockIdx.y;                // 0..31
    const int r0    = strip * ROWS_;
    if (tid < 64) whist[tid] = 0u;

    const float4* rb4 = (const float4*)(route + (size_t)b * HW_);
    const float4* ub4 = (const float4*)(unc   + (size_t)b * HW_);
    unsigned long long* hseg =
        hotlist + (size_t)(b * NSTRIP_ + strip) * HOTCAP_ + wid * HSEG_;

    // Stage 18 halo rows: branchless (slot clamp), 10 loads in flight.
    float4 rv[5], uv[5];
    int lrow[5], c4[5]; bool ok[5];
    #pragma unroll
    for (int k = 0; k < 5; ++k) {
        int slot = tid + k * THR_;
        slot = slot < 2303 ? slot : 2303;
        int row = slot >> 7;
        int gy  = r0 - 1 + row;
        lrow[k] = row; c4[k] = slot & 127;
        ok[k]   = (gy >= 0 && gy < H_);
        int cy  = gy < 0 ? 0 : (gy >= H_ ? H_ - 1 : gy);
        rv[k] = rb4[cy * 128 + c4[k]];
        uv[k] = ub4[cy * 128 + c4[k]];
    }
    #pragma unroll
    for (int k = 0; k < 5; ++k) {
        float4 s;
        s.x = score_ref(rv[k].x, uv[k].x);
        s.y = score_ref(rv[k].y, uv[k].y);
        s.z = score_ref(rv[k].z, uv[k].z);
        s.w = score_ref(rv[k].w, uv[k].w);
        if (!ok[k]) { s.x = -INFINITY; s.y = -INFINITY;
                      s.z = -INFINITY; s.w = -INFINITY; }
        *(float4*)&sm[lrow[k]][c4[k] * 4] = s;
    }
    __syncthreads();

    // Peak test: 16x512 interior, 4-px groups, float4 reads + column max.
    // Hot peaks (bits >= 0.5f): per-wave register ballot counter (no LDS
    // atomic, no shfl broadcast in the chain).
    const unsigned long long lt = (1ull << lane) - 1ull;
    int wn = 0;                                  // wave-uniform hot count
    #pragma unroll
    for (int j = 0; j < 4; ++j) {
        int g  = tid + j * THR_;                 // 0..2047
        int ly = 1 + (g >> 7);                   // 1..16
        int x0 = (g & 127) * 4;
        int gy = r0 + (ly - 1);
        float4 q0 = *(const float4*)&sm[ly - 1][x0];
        float4 q1 = *(const float4*)&sm[ly    ][x0];
        float4 q2 = *(const float4*)&sm[ly + 1][x0];
        bool hasL = (x0 > 0), hasR = (x0 + 4 < W_);
        float l0 = hasL ? sm[ly - 1][x0 - 1] : -INFINITY;
        float l1 = hasL ? sm[ly    ][x0 - 1] : -INFINITY;
        float l2 = hasL ? sm[ly + 1][x0 - 1] : -INFINITY;
        float e0 = hasR ? sm[ly - 1][x0 + 4] : -INFINITY;
        float e1 = hasR ? sm[ly    ][x0 + 4] : -INFINITY;
        float e2 = hasR ? sm[ly + 1][x0 + 4] : -INFINITY;
        float f_m1 = fmaxf(l0, fmaxf(l1, l2));
        float f_0  = fmaxf(q0.x, fmaxf(q1.x, q2.x));
        float f_1  = fmaxf(q0.y, fmaxf(q1.y, q2.y));
        float f_2  = fmaxf(q0.z, fmaxf(q1.z, q2.z));
        float f_3  = fmaxf(q0.w, fmaxf(q1.w, q2.w));
        float f_4  = fmaxf(e0, fmaxf(e1, e2));
        float tb0  = fmaxf(q0.x, q2.x);
        float tb1  = fmaxf(q0.y, q2.y);
        float tb2  = fmaxf(q0.z, q2.z);
        float tb3  = fmaxf(q0.w, q2.w);
        float vv[4] = { q1.x, q1.y, q1.z, q1.w };
        float mm[4];
        mm[0] = fmaxf(fmaxf(f_m1, f_1), tb0);
        mm[1] = fmaxf(fmaxf(f_0,  f_2), tb1);
        mm[2] = fmaxf(fmaxf(f_1,  f_3), tb2);
        mm[3] = fmaxf(fmaxf(f_2,  f_4), tb3);
        #pragma unroll
        for (int i = 0; i < 4; ++i) {
            bool take = (vv[i] >= mm[i]);
            unsigned int bits = __float_as_uint(vv[i]);
            bool hot = take && (bits >= HOTBITS_);
            unsigned long long hmk = __ballot(hot);
            if (hot) {
                int hp = wn + __popcll(hmk & lt);
                if (hp < HSEG_) {
                    unsigned int idx = (unsigned int)(gy * W_ + x0 + i);
                    hseg[hp] = ((unsigned long long)bits << 32)
                               | (0xFFFFFFFFu - idx);
                    atomicAdd(&whist[(bits >> 18) - WBASE_], 1u);
                }
            }
            wn += __popcll(hmk);
        }
    }
    // Zero-fill this wave's tail (select2 streams the region uncondition-
    // ally). Same total writes as R23's block-wide tail fill.
    {
        int stored = wn < HSEG_ ? wn : HSEG_;
        for (int i = stored + lane; i < HSEG_; i += 64) hseg[i] = 0ull;
    }
    __syncthreads();                             // whist complete

    // Plain coalesced store of this strip's 64-bucket window hist.
    if (tid < 64)
        ghw[(size_t)(b * NSTRIP_ + strip) * 64 + tid] = whist[tid];
}

// ---- select2: window hist -> T -> hot stream -> rank -> emit --------------
// LDS overlay: u_ holds sm[18][512] during the fallback strip loop, then
// cursor[4096] + grp[2048] afterwards (fast path uses only the latter).
__global__ __launch_bounds__(1024) void select2_kernel(
    const float* __restrict__ route, const float* __restrict__ unc_r,
    const float* __restrict__ scale, const float* __restrict__ unc,
    const unsigned long long* __restrict__ hotlist,
    const unsigned int* __restrict__ ghw,
    unsigned long long* __restrict__ fbbuf,
    const int* __restrict__ ih_p, const int* __restrict__ iw_p,
    float* __restrict__ out)
{
    __shared__ __align__(16) unsigned char u_[(ROWS_ + 2) * W_ * 4]; // 36.9 KB
    __shared__ unsigned int hist[NBUK_];                             // 16 KB
    __shared__ int sh_T, sh_nc, sh_fb, sh_fn;

    float (*sm)[W_] = (float (*)[W_])u_;
    unsigned int* cursor = (unsigned int*)u_;                        // 16 KB
    unsigned long long* grp = (unsigned long long*)(u_ + 16384);     // 16 KB

    const int b = blockIdx.x, tid = threadIdx.x;
    const int lane = tid & 63, wid = tid >> 6;
    const unsigned int* gbase = ghw + (size_t)b * NSTRIP_ * 64;

    // Phase A (fast): sum 32 per-strip window hists (8 KB read).
    if (tid == 0) { sh_fb = 0; sh_T = 1; sh_nc = 0; sh_fn = 0; }
    if (tid < 64) hist[WBASE_ + tid] = 0u;
    __syncthreads();
    {
        for (int i = tid; i < NSTRIP_ * 64; i += 1024) {
            unsigned int v = gbase[i];
            if (v) atomicAdd(&hist[WBASE_ + (i & 63)], v);
        }
    }
    __syncthreads();

    // Phase B (fast, wave0): T within the window, else flag fallback.
    if (wid == 0) {
        int cnt = (int)hist[WBASE_ + lane];
        int sum = cnt;
        #pragma unroll
        for (int off = 32; off > 0; off >>= 1)
            sum += __shfl_down(sum, off, 64);
        sum = __shfl(sum, 0, 64);
        if (sum < K_) {
            if (lane == 0) sh_fb = 1;
        } else {
            int suf = cnt;                       // inclusive suffix over lanes
            #pragma unroll
            for (int off = 1; off < 64; off <<= 1) {
                int o = __shfl_down(suf, off, 64);
                suf += (lane + off < 64) ? o : 0;
            }
            bool cond = suf >= K_;
            unsigned long long mask = __ballot(cond);
            int ls = 63 - __builtin_clzll(mask);
            if (lane >= ls) cursor[WBASE_ + lane] = (unsigned int)(suf - cnt);
            int ncv = __shfl(suf, ls, 64);
            if (lane == 0) { sh_T = WBASE_ + ls; sh_nc = ncv; }
        }
    }
    __syncthreads();
    const int fb = sh_fb;

    if (fb) {
        // ==== Fallback (never taken on sane data): full per-batch recompute.
        for (int i = tid; i < NBUK_; i += 1024) hist[i] = 0u;
        __syncthreads();

        const float4* rb4 = (const float4*)(route + (size_t)b * HW_);
        const float4* ub4 = (const float4*)(unc_r + (size_t)b * HW_);
        unsigned long long* fbb = fbbuf + (size_t)b * FBCAP_;

        for (int strip = 0; strip < NSTRIP_; ++strip) {
            const int r0 = strip * ROWS_;
            __syncthreads();                    // sm free from previous strip
            for (int slot = tid; slot < 2304; slot += 1024) {
                int row = slot >> 7;
                int gy  = r0 - 1 + row;
                int c4  = slot & 127;
                bool okr = (gy >= 0 && gy < H_);
                int cy  = gy < 0 ? 0 : (gy >= H_ ? H_ - 1 : gy);
                float4 r4 = rb4[cy * 128 + c4];
                float4 u4 = ub4[cy * 128 + c4];
                float4 s;
                s.x = score_ref(r4.x, u4.x);
                s.y = score_ref(r4.y, u4.y);
                s.z = score_ref(r4.z, u4.z);
                s.w = score_ref(r4.w, u4.w);
                if (!okr) { s.x = -INFINITY; s.y = -INFINITY;
                            s.z = -INFINITY; s.w = -INFINITY; }
                *(float4*)&sm[row][c4 * 4] = s;
            }
            __syncthreads();
            // Peak test over the 16x512 interior (4-px groups).
            for (int g = tid; g < 2048; g += 1024) {
                int ly = 1 + (g >> 7);           // 1..16
                int x0 = (g & 127) * 4;
                int gy = r0 + (ly - 1);
                float4 q0 = *(const float4*)&sm[ly - 1][x0];
                float4 q1 = *(const float4*)&sm[ly    ][x0];
                float4 q2 = *(const float4*)&sm[ly + 1][x0];
                bool hasL = (x0 > 0), hasR = (x0 + 4 < W_);
                float l0 = hasL ? sm[ly - 1][x0 - 1] : -INFINITY;
                float l1 = hasL ? sm[ly    ][x0 - 1] : -INFINITY;
                float l2 = hasL ? sm[ly + 1][x0 - 1] : -INFINITY;
                float e0 = hasR ? sm[ly - 1][x0 + 4] : -INFINITY;
                float e1 = hasR ? sm[ly    ][x0 + 4] : -INFINITY;
                float e2 = hasR ? sm[ly + 1][x0 + 4] : -INFINITY;
                float f_m1 = fmaxf(l0, fmaxf(l1, l2));
                float f_0  = fmaxf(q0.x, fmaxf(q1.x, q2.x));
                float f_1  = fmaxf(q0.y, fmaxf(q1.y, q2.y));
                float f_2  = fmaxf(q0.z, fmaxf(q1.z, q2.z));
                float f_3  = fmaxf(q0.w, fmaxf(q1.w, q2.w));
                float f_4  = fmaxf(e0, fmaxf(e1, e2));
                float tb0  = fmaxf(q0.x, q2.x);
                float tb1  = fmaxf(q0.y, q2.y);
                float tb2  = fmaxf(q0.z, q2.z);
                float tb3  = fmaxf(q0.w, q2.w);
                float vv[4] = { q1.x, q1.y, q1.z, q1.w };
                float mm[4];
                mm[0] = fmaxf(fmaxf(f_m1, f_1), tb0);
                mm[1] = fmaxf(fmaxf(f_0,  f_2), tb1);
                mm[2] = fmaxf(fmaxf(f_1,  f_3), tb2);
                mm[3] = fmaxf(fmaxf(f_2,  f_4), tb3);
                #pragma unroll
                for (int i = 0; i < 4; ++i) {
                    if (vv[i] >= mm[i]) {
                        unsigned int bits = __float_as_uint(vv[i]);
                        unsigned int idx  = (unsigned int)(gy * W_ + x0 + i);
                        int p = atomicAdd(&sh_fn, 1);
                        if (p < FBCAP_) {
                            fbb[p] = ((unsigned long long)bits << 32)
                                     | (0xFFFFFFFFu - idx);
                            atomicAdd(&hist[bits >> 18], 1u);
                        }
                    }
                }
            }
        }
        __syncthreads();                        // sm dead; hist complete

        // Full T-scan + cursor suffix-init (wave0).
        if (wid == 0) {
            int Tv = 0;
            int total = 0;
            for (int c = NBUK_ / 64 - 1; c >= 0; --c) {
                int cnt = (int)hist[c * 64 + lane];
                int sum = cnt;
                #pragma unroll
                for (int off = 32; off > 0; off >>= 1)
                    sum += __shfl_down(sum, off, 64);
                sum = __shfl(sum, 0, 64);
                if (total + sum < K_) { total += sum; continue; }
                int suf = cnt;
                #pragma unroll
                for (int off = 1; off < 64; off <<= 1) {
                    int o = __shfl_down(suf, off, 64);
                    suf += (lane + off < 64) ? o : 0;
                }
                bool cond = (total + suf) >= K_;
                unsigned long long mask = __ballot(cond);
                int ls = 63 - __builtin_clzll(mask);
                Tv = c * 64 + ls;
                break;
            }
            if (Tv < 1) Tv = 1;
            int run = 0;
            for (int cb = NBUK_ - 64; cb >= (Tv & ~63); cb -= 64) {
                int beta = cb + lane;
                int cnt = (beta >= Tv) ? (int)hist[beta] : 0;
                int suf = cnt;
                #pragma unroll
                for (int off = 1; off < 64; off <<= 1) {
                    int o = __shfl_down(suf, off, 64);
                    suf += (lane + off < 64) ? o : 0;
                }
                int chunk_total = __shfl(suf, 0, 64);
                if (beta >= Tv) cursor[beta] = (unsigned int)(run + (suf - cnt));
                run += chunk_total;
            }
            if (lane == 0) { sh_T = Tv; sh_nc = run; }
        }
    }
    __syncthreads();
    const unsigned int T = (unsigned int)sh_T;

    // Phase C: stream (hot list | fallback buffer) and scatter grouped.
    if (!fb) {
        const ulonglong2* src =
            (const ulonglong2*)(hotlist + (size_t)b * NSTRIP_ * HOTCAP_);
        for (int i = tid; i < HOTPAIR_; i += 1024) {
            ulonglong2 a = src[i];
            unsigned int b0 = (unsigned int)(a.x >> 50);
            unsigned int b1 = (unsigned int)(a.y >> 50);
            if (b0 >= T) {
                unsigned int pos = atomicAdd(&cursor[b0], 1u);
                if (pos < GCAP_) grp[pos] = a.x;
            }
            if (b1 >= T) {
                unsigned int pos = atomicAdd(&cursor[b1], 1u);
                if (pos < GCAP_) grp[pos] = a.y;
            }
        }
    } else {
        const unsigned long long* fbb = fbbuf + (size_t)b * FBCAP_;
        int n = sh_fn; if (n > FBCAP_) n = FBCAP_;
        for (int i = tid; i < n; i += 1024) {
            unsigned long long k = fbb[i];
            unsigned int b0 = (unsigned int)(k >> 50);
            if (b0 >= T) {
                unsigned int pos = atomicAdd(&cursor[b0], 1u);
                if (pos < GCAP_) grp[pos] = k;
            }
        }
    }
    __syncthreads();

    // Phase D: exact descending rank per candidate + direct emit.
    // rank = (#elements in higher buckets) + (#same-bucket keys > mine).
    // Keys unique (idx in low bits) -> identical order to a full desc sort.
    const float fih = (float)(*ih_p);
    const float fiw = (float)(*iw_p);
    float* rois   = out;                       // [B,K,5]
    float* scores = out + (size_t)B_ * K_ * 5; // [B,K]
    float* validf = out + (size_t)B_ * K_ * 6; // [B,K]

    int nc = sh_nc;
    int ncEff = nc < GCAP_ ? nc : GCAP_;
    for (int p = tid; p < ncEff; p += 1024) {
        unsigned long long key = grp[p];
        unsigned int beta = (unsigned int)(key >> 50);
        int segEnd   = (int)cursor[beta];         // start + cnt
        int segStart = segEnd - (int)hist[beta];
        int qEnd = segEnd < GCAP_ ? segEnd : GCAP_;
        int r = 0;
        for (int q = segStart; q < qEnd; ++q)
            r += (grp[q] > key) ? 1 : 0;
        int rank = segStart + r;
        if (rank < K_) {
            int o = b * K_ + rank;
            unsigned int bits = (unsigned int)(key >> 32);
            float v = __uint_as_float(bits);
            unsigned int idx = 0xFFFFFFFFu - (unsigned int)(key & 0xFFFFFFFFull);
            int y = (int)(idx >> 9), x = (int)(idx & 511u);
            float cx = ((float)x + 0.5f) * 4.0f;
            float cy = ((float)y + 0.5f) * 4.0f;
            float ss = sigmoid_fast(scale[(size_t)b * HW_ + idx]);
            float su = sigmoid_fast(unc  [(size_t)b * HW_ + idx]);
            float side = (32.0f + ss * 480.0f) * (1.0f + 0.25f * su);
            float half = 0.5f * side;
            float x1 = fminf(fmaxf(cx - half, 0.0f), fiw - 1.0f);
            float y1 = fminf(fmaxf(cy - half, 0.0f), fih - 1.0f);
            float x2 = fminf(fmaxf(cx + half, 1.0f), fiw);
            float y2 = fminf(fmaxf(cy + half, 1.0f), fih);
            rois[o * 5 + 0] = (float)b;
            rois[o * 5 + 1] = x1; rois[o * 5 + 2] = y1;
            rois[o * 5 + 3] = x2; rois[o * 5 + 4] = y2;
            scores[o] = v; validf[o] = 1.0f;
        }
    }
    // Tail fill (only if fewer than K candidates exist — normally empty).
    for (int k = nc + tid; k < K_; k += 1024) {
        int o = b * K_ + k;
        rois[o * 5 + 0] = 0.0f; rois[o * 5 + 1] = 0.0f;
        rois[o * 5 + 2] = 0.0f; rois[o * 5 + 3] = 0.0f;
        rois[o * 5 + 4] = 0.0f;
        scores[o] = 0.0f; validf[o] = 0.0f;
    }
}

extern "C" void kernel_launch(void* const* d_in, const int* in_sizes, int n_in,
                              void* d_out, int out_size, void* d_ws, size_t ws_size,
                              hipStream_t stream) {
    const float* route = (const float*)d_in[0];
    const float* scale = (const float*)d_in[1];
    const float* unc   = (const float*)d_in[2];
    const int*   ih    = (const int*)d_in[3];
    const int*   iw    = (const int*)d_in[4];
    float* out = (float*)d_out;

    // ws layout (all fast-path regions fully rewritten each launch):
    //   hotlist  8,388,608 B (32 x 32 x 1024 u64)  — per-wave hot sub-segs
    //   ghw        262,144 B (32 x 32 x 64 u32)    — window hists
    //   fbbuf   11,534,336 B (32 x 45056 u64)      — fallback only
    unsigned char* base = (unsigned char*)d_ws;
    unsigned long long* hotlist = (unsigned long long*)base;
    unsigned int* ghw = (unsigned int*)(base + HL_BYTES_);
    unsigned long long* fbbuf =
        (unsigned long long*)(base + HL_BYTES_ + GW_BYTES_);

    dim3 g(NSTRIP_, B_);      // 32 strips x 32 batches
    fused_peak_kernel<<<g, THR_, 0, stream>>>(route, unc, hotlist, ghw);
    select2_kernel<<<B_, 1024, 0, stream>>>(route, unc, scale, unc,
                                            hotlist, ghw, fbbuf,
                                            ih, iw, out);
}